// Round 4
// baseline (223.814 us; speedup 1.0000x reference)
//
#include <hip/hip_runtime.h>
#include <hip/hip_bf16.h>
#include <stdint.h>

// B=8, N=1024, D=1024.  out = relu(adj @ (y@W) / adj_sumrow + b + x)
// R7: 256x256xBK64 tile, 512 thr / 8 waves (2Mx4N, 128x64 per wave, acc[8][4]).
// 4 quadrant-phases per K-tile; each phase stages ONE 16KB chunk of the next
// tile and waits counted vmcnt(4)+bar for exactly the chunk it needs
// (issue order A0,B0,B1,A1 == quadrant need order q00,q01,q11,q10).
// Loads never drain to 0 in the main loop. 64 MFMA/wave/K-tile (4x R6's
// amortization per barrier-phase — the R3-R6 invariant was per-phase cost).
// XCD-bijective grids keep R6's L2 locality (FETCH 90->41MB, proven).

typedef float  f32x4  __attribute__((ext_vector_type(4)));
typedef __bf16 bf16x8 __attribute__((ext_vector_type(8)));

__device__ __forceinline__ unsigned short f2bf(float f) {
  union { float f; unsigned int u; } c; c.f = f;
  unsigned int u = c.u;
  u += 0x7FFFu + ((u >> 16) & 1u);   // RNE; inputs finite
  return (unsigned short)(u >> 16);
}

__device__ __forceinline__ void async_cp16(const void* g, void* l) {
  __builtin_amdgcn_global_load_lds(
      (const __attribute__((address_space(1))) unsigned int*)g,
      (__attribute__((address_space(3))) unsigned int*)l, 16, 0, 0);
}

__device__ __forceinline__ void bar() { asm volatile("s_barrier" ::: "memory"); }
#define VMCNT(n) asm volatile("s_waitcnt vmcnt(" #n ")" ::: "memory")

// ---------------- fused pre-pass (unchanged) ----------------

__global__ __launch_bounds__(256) void k_prep(
    const float4* __restrict__ y4, const float4* __restrict__ a4,
    ushort4* __restrict__ yb, ushort4* __restrict__ ab,
    const float* __restrict__ W, unsigned short* __restrict__ Wt)
{
  __shared__ float t[64][65];
  const int bid = blockIdx.x;
  if (bid < 16384) {
    const int i = bid * 256 + threadIdx.x;
    const bool isY = i < 2097152;
    const float4 v = isY ? y4[i] : a4[i - 2097152];
    ushort4 p;
    p.x = f2bf(v.x); p.y = f2bf(v.y); p.z = f2bf(v.z); p.w = f2bf(v.w);
    if (isY) yb[i] = p; else ab[i - 2097152] = p;
  } else {
    const int id = bid - 16384;
    const int n0 = (id & 15) * 64, k0 = (id >> 4) * 64;
    const int tx = threadIdx.x & 63, ty = threadIdx.x >> 6;
#pragma unroll
    for (int r = ty; r < 64; r += 4)
      t[r][tx] = W[(size_t)(k0 + r) * 1024 + n0 + tx];
    __syncthreads();
#pragma unroll
    for (int r = ty; r < 64; r += 4)
      Wt[(size_t)(n0 + r) * 1024 + k0 + tx] = f2bf(t[tx][r]);
  }
}

// ---------------- GEMM pieces: 256x256 tile, BK=64 ----------------
// LDS row = 128B = 8 chunks of 16B; physical chunk = (logical + row) & 7.
// Staging applies the inverse permutation on the global k-column (free);
// all staging row bases are multiples of 8 so the mod-8 algebra is unchanged
// from the verified R3-R6 primitives.
//
// A-chunk c (c in {0,1}) = rows { r : (r>>6)&1 == c }  (two 64-row runs)
// B-chunk c             = rows { r : (r>>5)&1 == c }  (four 32-row runs)
// -> quadrant (mh,nh) across ALL waves touches exactly A-chunk mh, B-chunk nh.

__device__ __forceinline__ void stageA(
    const unsigned short* __restrict__ A, int sA, int m0, int k0, int c,
    unsigned short* la, int wave, int rg, int colo)
{
#pragma unroll
  for (int s = 0; s < 2; ++s) {
    const int t = wave * 2 + s;                        // 0..15
    const int row0 = (t >> 3) * 128 + c * 64 + (t & 7) * 8;
    async_cp16(A + (size_t)(m0 + row0 + rg) * sA + k0 + colo, la + row0 * 64);
  }
}

__device__ __forceinline__ void stageB(
    const unsigned short* __restrict__ Bt, int sB, int n0, int k0, int c,
    unsigned short* lb, int wave, int rg, int colo)
{
#pragma unroll
  for (int s = 0; s < 2; ++s) {
    const int t = wave * 2 + s;                        // 0..15
    const int row0 = (t >> 2) * 64 + c * 32 + (t & 3) * 8;
    async_cp16(Bt + (size_t)(n0 + row0 + rg) * sB + k0 + colo, lb + row0 * 64);
  }
}

__device__ __forceinline__ void readA(
    const unsigned short* la, bf16x8 af[2][4], int wm, int mh, int quad, int l16)
{
#pragma unroll
  for (int h = 0; h < 2; ++h)
#pragma unroll
    for (int i = 0; i < 4; ++i) {
      const int r = wm + mh * 64 + i * 16 + l16;
      af[h][i] = *(const bf16x8*)(la + r * 64 + ((h * 4 + quad + r) & 7) * 8);
    }
}

__device__ __forceinline__ void readB(
    const unsigned short* lb, bf16x8 bfr[2][2], int wn, int nh, int quad, int l16)
{
#pragma unroll
  for (int h = 0; h < 2; ++h)
#pragma unroll
    for (int j = 0; j < 2; ++j) {
      const int r = wn + nh * 32 + j * 16 + l16;
      bfr[h][j] = *(const bf16x8*)(lb + r * 64 + ((h * 4 + quad + r) & 7) * 8);
    }
}

__device__ __forceinline__ void quad16(
    bf16x8 af[2][4], bf16x8 bfr[2][2], f32x4 acc[8][4], int mh, int nh)
{
  __builtin_amdgcn_s_setprio(1);
#pragma unroll
  for (int h = 0; h < 2; ++h)
#pragma unroll
    for (int i = 0; i < 4; ++i)
#pragma unroll
      for (int j = 0; j < 2; ++j)
        acc[mh * 4 + i][nh * 2 + j] = __builtin_amdgcn_mfma_f32_16x16x32_bf16(
            af[h][i], bfr[h][j], acc[mh * 4 + i][nh * 2 + j], 0, 0, 0);
  __builtin_amdgcn_s_setprio(0);
}

// 16 K-tiles. Compute tile T from buf[T&1] while staging tile T+1 into the
// other buffer, one 16KB chunk per quadrant-phase. vmcnt(4)+bar makes the
// needed chunk globally visible (counted-wait + barrier => cross-wave).
__device__ __forceinline__ void gemm256(
    const unsigned short* __restrict__ A,  int sA,
    const unsigned short* __restrict__ Bt, int sB,
    int m0, int n0, f32x4 acc[8][4], unsigned short* lsm, int tid)
{
  const int lane = tid & 63, wave = tid >> 6;
  const int wm = (wave >> 2) * 128, wn = (wave & 3) * 64;
  const int quad = lane >> 4, l16 = lane & 15;
  const int rg = lane >> 3;
  const int colo = (((lane & 7) - rg) & 7) * 8;   // inverse-swizzled k-offset

  bf16x8 af[2][4], bfr[2][2];

  // prologue: tile 0, issue order A0,B0,B1,A1 (matches steady state)
  stageA(A, sA, m0, 0, 0, lsm,        wave, rg, colo);
  stageB(Bt, sB, n0, 0, 0, lsm + 16384, wave, rg, colo);
  stageB(Bt, sB, n0, 0, 1, lsm + 16384, wave, rg, colo);
  stageA(A, sA, m0, 0, 1, lsm,        wave, rg, colo);

#pragma unroll 1
  for (int T = 0; T < 15; ++T) {
    const unsigned short* la = lsm + (T & 1) * 32768;
    const unsigned short* lb = la + 16384;
    unsigned short* na = lsm + ((T + 1) & 1) * 32768;
    unsigned short* nb = na + 16384;
    const int nk = (T + 1) * 64;

    // ph0 (q00): needs A0(T),B0(T); keeps newest {B1(T),A1(T)} in flight
    VMCNT(4); bar();
    stageA(A, sA, m0, nk, 0, na, wave, rg, colo);
    readA(la, af, wm, 0, quad, l16);
    readB(lb, bfr, wn, 0, quad, l16);
    quad16(af, bfr, acc, 0, 0);

    // ph1 (q01): needs B1(T); af(A0) register-carried
    VMCNT(4); bar();
    stageB(Bt, sB, n0, nk, 0, nb, wave, rg, colo);
    readB(lb, bfr, wn, 1, quad, l16);
    quad16(af, bfr, acc, 0, 1);

    // ph2 (q11): needs A1(T); bfr(B1) register-carried
    VMCNT(4); bar();
    stageB(Bt, sB, n0, nk, 1, nb, wave, rg, colo);
    readA(la, af, wm, 1, quad, l16);
    quad16(af, bfr, acc, 1, 1);

    // ph3 (q10): everything already resident -> no wait, no barrier
    stageA(A, sA, m0, nk, 1, na, wave, rg, colo);
    readB(lb, bfr, wn, 0, quad, l16);
    quad16(af, bfr, acc, 1, 0);
  }

  // tail: tile 15, nothing left to stage; drain with tightening counts
  {
    const unsigned short* la = lsm + 32768;   // 15&1 == 1
    const unsigned short* lb = la + 16384;
    VMCNT(4); bar();
    readA(la, af, wm, 0, quad, l16);
    readB(lb, bfr, wn, 0, quad, l16);
    quad16(af, bfr, acc, 0, 0);
    VMCNT(2); bar();
    readB(lb, bfr, wn, 1, quad, l16);
    quad16(af, bfr, acc, 0, 1);
    VMCNT(0); bar();
    readA(la, af, wm, 1, quad, l16);
    quad16(af, bfr, acc, 1, 1);
    readB(lb, bfr, wn, 0, quad, l16);
    quad16(af, bfr, acc, 1, 0);
  }
}

__device__ __forceinline__ void zero_acc(f32x4 acc[8][4]) {
#pragma unroll
  for (int i = 0; i < 8; ++i)
#pragma unroll
    for (int j = 0; j < 4; ++j)
#pragma unroll
      for (int r = 0; r < 4; ++r) acc[i][j][r] = 0.0f;
}

// ---------------- GEMM1: Sup2[d][b*1024+n] = (y@W)^T ----------------
// 128 blocks; xcd = bid&7 owns n-tiles [xcd*4, xcd*4+4) -> per-XCD working
// set Wt (2MB) + ybf n-slice (2MB) = one L2.

__global__ __launch_bounds__(512, 2) void k_gemm1(
    const unsigned short* __restrict__ Wt,    // [1024][1024]
    const unsigned short* __restrict__ Ybf,   // [8192][1024]
    unsigned short* __restrict__ Sup2)        // [1024][8192]
{
  __shared__ __align__(16) unsigned short lsm[65536];  // 128 KB
  const int tid = threadIdx.x;
  const int xcd = blockIdx.x & 7, slot = blockIdx.x >> 3;  // slot 0..15
  const int m0 = (slot >> 2) * 256;
  const int n0 = (xcd * 4 + (slot & 3)) * 256;

  f32x4 acc[8][4];
  zero_acc(acc);
  gemm256(Wt, 1024, Ybf, 1024, m0, n0, acc, lsm, tid);

  const int lane = tid & 63, wave = tid >> 6;
  const int wm = (wave >> 2) * 128, wn = (wave & 3) * 64;
  const int quad = lane >> 4, l16 = lane & 15;
#pragma unroll
  for (int mi = 0; mi < 8; ++mi) {
    const int mb = m0 + wm + mi * 16 + quad * 4;
#pragma unroll
    for (int r = 0; r < 4; ++r) {
      unsigned short* row = Sup2 + ((size_t)(mb + r) << 13);
#pragma unroll
      for (int nj = 0; nj < 4; ++nj)
        row[n0 + wn + nj * 16 + l16] = f2bf(acc[mi][nj][r]);
    }
  }
}

// ------- GEMM2: out = relu(adj@support / rowsum + bias + x) -------
// 128 blocks; xcd = bid&7 owns batch b=xcd -> adjbf[b] (2MB) + sup2 b-slice
// (2MB) = one L2.

__global__ __launch_bounds__(512, 2) void k_gemm2(
    const unsigned short* __restrict__ AdjBf, // [8][1024][1024]
    const unsigned short* __restrict__ Sup2,  // [1024][8192]
    const float* __restrict__ x,
    const float* __restrict__ sumrow,         // [8][1024]
    const float* __restrict__ bias,           // [1024]
    float* __restrict__ out)
{
  __shared__ __align__(16) unsigned short lsm[65536];  // 128 KB
  const int tid = threadIdx.x;
  const int b = blockIdx.x & 7, slot = blockIdx.x >> 3;  // slot 0..15
  const int m0 = (slot >> 2) * 256, n0 = (slot & 3) * 256;

  f32x4 acc[8][4];
  zero_acc(acc);
  gemm256(AdjBf + ((size_t)b << 20), 1024,
          Sup2 + ((size_t)b << 10), 8192,
          m0, n0, acc, lsm, tid);

  const float* xb = x   + ((size_t)b << 20);
  float*       ob = out + ((size_t)b << 20);
  const float* sr = sumrow + ((size_t)b << 10);
  const int lane = tid & 63, wave = tid >> 6;
  const int wm = (wave >> 2) * 128, wn = (wave & 3) * 64;
  const int quad = lane >> 4, l16 = lane & 15;

  float bv[4];
#pragma unroll
  for (int nj = 0; nj < 4; ++nj) bv[nj] = bias[n0 + wn + nj * 16 + l16];

#pragma unroll
  for (int mi = 0; mi < 8; ++mi) {
    const int mb = m0 + wm + mi * 16 + quad * 4;
#pragma unroll
    for (int r = 0; r < 4; ++r) {
      const int m = mb + r;
      const float inv = 1.0f / sr[m];
#pragma unroll
      for (int nj = 0; nj < 4; ++nj) {
        const int n = n0 + wn + nj * 16 + l16;
        const size_t idx = (((size_t)m) << 10) + n;
        float v = acc[mi][nj][r] * inv + bv[nj] + xb[idx];
        ob[idx] = fmaxf(v, 0.0f);
      }
    }
  }
}

// ---------------- launcher ----------------

extern "C" void kernel_launch(void* const* d_in, const int* in_sizes, int n_in,
                              void* d_out, int out_size, void* d_ws, size_t ws_size,
                              hipStream_t stream) {
  const float* x      = (const float*)d_in[0];
  const float* y      = (const float*)d_in[1];
  const float* adj    = (const float*)d_in[2];
  const float* sumrow = (const float*)d_in[3];
  const float* W      = (const float*)d_in[4];
  const float* bias   = (const float*)d_in[5];
  float* out = (float*)d_out;

  char* ws = (char*)d_ws;
  unsigned short* ybf   = (unsigned short*)(ws);                       // 16 MB
  unsigned short* adjbf = (unsigned short*)(ws + ((size_t)16 << 20));  // 16 MB
  unsigned short* wt    = (unsigned short*)(ws + ((size_t)32 << 20));  //  2 MB
  unsigned short* sup2  = (unsigned short*)(ws + ((size_t)34 << 20));  // 16 MB

  k_prep<<<dim3(16640), dim3(256), 0, stream>>>(
      (const float4*)y, (const float4*)adj, (ushort4*)ybf, (ushort4*)adjbf, W, wt);
  k_gemm1<<<dim3(128), dim3(512), 0, stream>>>(wt, ybf, sup2);
  k_gemm2<<<dim3(128), dim3(512), 0, stream>>>(adjbf, sup2, x, sumrow, bias, out);
}

// Round 5
// 195.677 us; speedup vs baseline: 1.1438x; 1.1438x over previous
//
#include <hip/hip_runtime.h>
#include <hip/hip_bf16.h>
#include <stdint.h>

// B=8, N=1024, D=1024.  out = relu(adj @ (y@W) / adj_sumrow + b + x)
// R8: R7's quadrant-phase counted-vmcnt schedule (1.48x better per-CU than
// the 2-barrier loop) with the grid fixed: BM=256 BN=128 BK=64 -> 256 blocks
// = 1/CU for BOTH gemms (R7's 128-block grid left half the machine idle).
// 8 waves 4Mx2N, 64x64/wave, acc[4][4]. Per K-tile: 3 staged 16KB chunks
// (A0,B,A1) interleaved across 4 phases, 2 counted waits + 2 barriers only,
// loads never drain to 0. LDS 96KB. XCD-bijective grids keep L2 residency.

typedef float  f32x4  __attribute__((ext_vector_type(4)));
typedef __bf16 bf16x8 __attribute__((ext_vector_type(8)));

__device__ __forceinline__ unsigned short f2bf(float f) {
  union { float f; unsigned int u; } c; c.f = f;
  unsigned int u = c.u;
  u += 0x7FFFu + ((u >> 16) & 1u);   // RNE; inputs finite
  return (unsigned short)(u >> 16);
}

__device__ __forceinline__ void async_cp16(const void* g, void* l) {
  __builtin_amdgcn_global_load_lds(
      (const __attribute__((address_space(1))) unsigned int*)g,
      (__attribute__((address_space(3))) unsigned int*)l, 16, 0, 0);
}

__device__ __forceinline__ void bar() { asm volatile("s_barrier" ::: "memory"); }
#define VMCNT(n) asm volatile("s_waitcnt vmcnt(" #n ")" ::: "memory")

// ---------------- fused pre-pass (unchanged) ----------------

__global__ __launch_bounds__(256) void k_prep(
    const float4* __restrict__ y4, const float4* __restrict__ a4,
    ushort4* __restrict__ yb, ushort4* __restrict__ ab,
    const float* __restrict__ W, unsigned short* __restrict__ Wt)
{
  __shared__ float t[64][65];
  const int bid = blockIdx.x;
  if (bid < 16384) {
    const int i = bid * 256 + threadIdx.x;
    const bool isY = i < 2097152;
    const float4 v = isY ? y4[i] : a4[i - 2097152];
    ushort4 p;
    p.x = f2bf(v.x); p.y = f2bf(v.y); p.z = f2bf(v.z); p.w = f2bf(v.w);
    if (isY) yb[i] = p; else ab[i - 2097152] = p;
  } else {
    const int id = bid - 16384;
    const int n0 = (id & 15) * 64, k0 = (id >> 4) * 64;
    const int tx = threadIdx.x & 63, ty = threadIdx.x >> 6;
#pragma unroll
    for (int r = ty; r < 64; r += 4)
      t[r][tx] = W[(size_t)(k0 + r) * 1024 + n0 + tx];
    __syncthreads();
#pragma unroll
    for (int r = ty; r < 64; r += 4)
      Wt[(size_t)(n0 + r) * 1024 + k0 + tx] = f2bf(t[tx][r]);
  }
}

// ---------------- GEMM pieces: 256x128 tile, BK=64, 8 waves ----------------
// LDS row = 128B = 8 chunks of 16B; physical chunk = (logical + row) & 7.
// Staging applies the inverse permutation on the global k-column; all staging
// row bases are multiples of 8 so the mod-8 algebra is unchanged (proven R3+).
//
// A-tile 256x64 = 32KB, two 16KB chunks: chunk c = rows with (r>>5)&1 == c
// (matches quadrant mh row sets under the 4Mx2N wave split).
// B-tile 128x64 = 16KB, one chunk (all rows).

__device__ __forceinline__ void stageA(
    const unsigned short* __restrict__ A, int sA, int m0, int k0, int c,
    unsigned short* la, int wave, int rg, int colo)
{
#pragma unroll
  for (int s = 0; s < 2; ++s) {
    const int t = wave * 2 + s;                        // 0..15
    const int row0 = (t >> 2) * 64 + c * 32 + (t & 3) * 8;
    async_cp16(A + (size_t)(m0 + row0 + rg) * sA + k0 + colo, la + row0 * 64);
  }
}

__device__ __forceinline__ void stageB(
    const unsigned short* __restrict__ Bt, int sB, int n0, int k0,
    unsigned short* lb, int wave, int rg, int colo)
{
#pragma unroll
  for (int s = 0; s < 2; ++s) {
    const int t = wave * 2 + s;                        // 0..15
    const int row0 = t * 8;
    async_cp16(Bt + (size_t)(n0 + row0 + rg) * sB + k0 + colo, lb + row0 * 64);
  }
}

__device__ __forceinline__ void readA(
    const unsigned short* la, bf16x8 af[2][2], int wm, int mh, int quad, int l16)
{
#pragma unroll
  for (int h = 0; h < 2; ++h)
#pragma unroll
    for (int i = 0; i < 2; ++i) {
      const int r = wm + mh * 32 + i * 16 + l16;
      af[h][i] = *(const bf16x8*)(la + r * 64 + ((h * 4 + quad + r) & 7) * 8);
    }
}

__device__ __forceinline__ void readB(
    const unsigned short* lb, bf16x8 bfr[2][2], int wn, int nh, int quad, int l16)
{
#pragma unroll
  for (int h = 0; h < 2; ++h)
#pragma unroll
    for (int j = 0; j < 2; ++j) {
      const int r = wn + nh * 32 + j * 16 + l16;
      bfr[h][j] = *(const bf16x8*)(lb + r * 64 + ((h * 4 + quad + r) & 7) * 8);
    }
}

__device__ __forceinline__ void quad8(
    bf16x8 af[2][2], bf16x8 bfr[2][2], f32x4 acc[4][4], int mh, int nh)
{
  __builtin_amdgcn_s_setprio(1);
#pragma unroll
  for (int h = 0; h < 2; ++h)
#pragma unroll
    for (int i = 0; i < 2; ++i)
#pragma unroll
      for (int j = 0; j < 2; ++j)
        acc[mh * 2 + i][nh * 2 + j] = __builtin_amdgcn_mfma_f32_16x16x32_bf16(
            af[h][i], bfr[h][j], acc[mh * 2 + i][nh * 2 + j], 0, 0, 0);
  __builtin_amdgcn_s_setprio(0);
}

// 16 K-tiles, double-buffered. Per tile T (steady state):
//  ph0: issue A0(T+1); vmcnt(4) [drain A0(T),B(T); keep A1(T),A0(T+1)]; bar;
//       q00 (readA0 + readB0)
//  ph1: issue B(T+1); no wait; q01 (readB1, af carried)
//  ph2: issue A1(T+1); vmcnt(6) [drain A1(T); keep 3 chunks]; bar;
//       q11 (readA1, bfr carried)
//  ph3: q10 (re-read B0, af carried) -- no wait, no barrier
// WAR-safety: each region's last read completes (MFMA-consumed) before a
// barrier that precedes the re-write's issue.
__device__ __forceinline__ void gemm256x128(
    const unsigned short* __restrict__ A,  int sA,
    const unsigned short* __restrict__ Bt, int sB,
    int m0, int n0, f32x4 acc[4][4], unsigned short* lsm, int tid)
{
  const int lane = tid & 63, wave = tid >> 6;
  const int wm = (wave >> 1) * 64, wn = (wave & 1) * 64;
  const int quad = lane >> 4, l16 = lane & 15;
  const int rg = lane >> 3;
  const int colo = (((lane & 7) - rg) & 7) * 8;   // inverse-swizzled k-offset

  bf16x8 af[2][2], bfr[2][2];

  // prologue: tile 0, issue order A0,B,A1 (matches steady-state drain order)
  stageA(A, sA, m0, 0, 0, lsm, wave, rg, colo);
  stageB(Bt, sB, n0, 0, lsm + 16384, wave, rg, colo);
  stageA(A, sA, m0, 0, 1, lsm, wave, rg, colo);

#pragma unroll 1
  for (int T = 0; T < 15; ++T) {
    const unsigned short* la = lsm + (T & 1) * 24576;
    const unsigned short* lb = la + 16384;
    unsigned short* na = lsm + ((T + 1) & 1) * 24576;
    unsigned short* nb = na + 16384;
    const int nk = (T + 1) * 64;

    // ph0 (q00)
    stageA(A, sA, m0, nk, 0, na, wave, rg, colo);
    VMCNT(4); bar();
    readA(la, af, wm, 0, quad, l16);
    readB(lb, bfr, wn, 0, quad, l16);
    quad8(af, bfr, acc, 0, 0);

    // ph1 (q01): B fully resident; af register-carried
    stageB(Bt, sB, n0, nk, nb, wave, rg, colo);
    readB(lb, bfr, wn, 1, quad, l16);
    quad8(af, bfr, acc, 0, 1);

    // ph2 (q11): needs A1(T); bfr register-carried
    stageA(A, sA, m0, nk, 1, na, wave, rg, colo);
    VMCNT(6); bar();
    readA(la, af, wm, 1, quad, l16);
    quad8(af, bfr, acc, 1, 1);

    // ph3 (q10): everything resident -> no wait, no barrier
    readB(lb, bfr, wn, 0, quad, l16);
    quad8(af, bfr, acc, 1, 0);
  }

  // tail: tile 15, nothing left to stage; tightening counts
  {
    const unsigned short* la = lsm + 24576;   // 15&1 == 1
    const unsigned short* lb = la + 16384;
    VMCNT(2); bar();
    readA(la, af, wm, 0, quad, l16);
    readB(lb, bfr, wn, 0, quad, l16);
    quad8(af, bfr, acc, 0, 0);
    readB(lb, bfr, wn, 1, quad, l16);
    quad8(af, bfr, acc, 0, 1);
    VMCNT(0); bar();
    readA(la, af, wm, 1, quad, l16);
    quad8(af, bfr, acc, 1, 1);
    readB(lb, bfr, wn, 0, quad, l16);
    quad8(af, bfr, acc, 1, 0);
  }
}

__device__ __forceinline__ void zero_acc(f32x4 acc[4][4]) {
#pragma unroll
  for (int i = 0; i < 4; ++i)
#pragma unroll
    for (int j = 0; j < 4; ++j)
#pragma unroll
      for (int r = 0; r < 4; ++r) acc[i][j][r] = 0.0f;
}

// ---------------- GEMM1: Sup2[d][b*1024+n] = (y@W)^T ----------------
// 256 blocks; xcd = bid&7 owns 8 consecutive n-tiles -> per-XCD working set
// Wt (2MB) + ybf n-slice (2MB) = one L2.

__global__ __launch_bounds__(512, 2) void k_gemm1(
    const unsigned short* __restrict__ Wt,    // [1024][1024]
    const unsigned short* __restrict__ Ybf,   // [8192][1024]
    unsigned short* __restrict__ Sup2)        // [1024][8192]
{
  __shared__ __align__(16) unsigned short lsm[49152];  // 96 KB
  const int tid = threadIdx.x;
  const int xcd = blockIdx.x & 7, slot = blockIdx.x >> 3;  // slot 0..31
  const int m0 = (slot >> 3) * 256;                        // 4 m-tiles
  const int n0 = (xcd * 8 + (slot & 7)) * 128;             // 64 n-tiles

  f32x4 acc[4][4];
  zero_acc(acc);
  gemm256x128(Wt, 1024, Ybf, 1024, m0, n0, acc, lsm, tid);

  const int lane = tid & 63, wave = tid >> 6;
  const int wm = (wave >> 1) * 64, wn = (wave & 1) * 64;
  const int quad = lane >> 4, l16 = lane & 15;
#pragma unroll
  for (int mi = 0; mi < 4; ++mi) {
    const int mb = m0 + wm + mi * 16 + quad * 4;
#pragma unroll
    for (int r = 0; r < 4; ++r) {
      unsigned short* row = Sup2 + ((size_t)(mb + r) << 13);
#pragma unroll
      for (int nj = 0; nj < 4; ++nj)
        row[n0 + wn + nj * 16 + l16] = f2bf(acc[mi][nj][r]);
    }
  }
}

// ------- GEMM2: out = relu(adj@support / rowsum + bias + x) -------
// 256 blocks; xcd = bid&7 owns batch b -> adjbf[b] (2MB) + sup2 b-slice (2MB)
// = one L2.

__global__ __launch_bounds__(512, 2) void k_gemm2(
    const unsigned short* __restrict__ AdjBf, // [8][1024][1024]
    const unsigned short* __restrict__ Sup2,  // [1024][8192]
    const float* __restrict__ x,
    const float* __restrict__ sumrow,         // [8][1024]
    const float* __restrict__ bias,           // [1024]
    float* __restrict__ out)
{
  __shared__ __align__(16) unsigned short lsm[49152];  // 96 KB
  const int tid = threadIdx.x;
  const int b = blockIdx.x & 7, slot = blockIdx.x >> 3;  // slot 0..31
  const int m0 = (slot >> 3) * 256, n0 = (slot & 7) * 128;

  f32x4 acc[4][4];
  zero_acc(acc);
  gemm256x128(AdjBf + ((size_t)b << 20), 1024,
              Sup2 + ((size_t)b << 10), 8192,
              m0, n0, acc, lsm, tid);

  const float* xb = x   + ((size_t)b << 20);
  float*       ob = out + ((size_t)b << 20);
  const float* sr = sumrow + ((size_t)b << 10);
  const int lane = tid & 63, wave = tid >> 6;
  const int wm = (wave >> 1) * 64, wn = (wave & 1) * 64;
  const int quad = lane >> 4, l16 = lane & 15;

  float bv[4];
#pragma unroll
  for (int nj = 0; nj < 4; ++nj) bv[nj] = bias[n0 + wn + nj * 16 + l16];

#pragma unroll
  for (int mi = 0; mi < 4; ++mi) {
    const int mb = m0 + wm + mi * 16 + quad * 4;
#pragma unroll
    for (int r = 0; r < 4; ++r) {
      const int m = mb + r;
      const float inv = 1.0f / sr[m];
#pragma unroll
      for (int nj = 0; nj < 4; ++nj) {
        const int n = n0 + wn + nj * 16 + l16;
        const size_t idx = (((size_t)m) << 10) + n;
        float v = acc[mi][nj][r] * inv + bv[nj] + xb[idx];
        ob[idx] = fmaxf(v, 0.0f);
      }
    }
  }
}

// ---------------- launcher ----------------

extern "C" void kernel_launch(void* const* d_in, const int* in_sizes, int n_in,
                              void* d_out, int out_size, void* d_ws, size_t ws_size,
                              hipStream_t stream) {
  const float* x      = (const float*)d_in[0];
  const float* y      = (const float*)d_in[1];
  const float* adj    = (const float*)d_in[2];
  const float* sumrow = (const float*)d_in[3];
  const float* W      = (const float*)d_in[4];
  const float* bias   = (const float*)d_in[5];
  float* out = (float*)d_out;

  char* ws = (char*)d_ws;
  unsigned short* ybf   = (unsigned short*)(ws);                       // 16 MB
  unsigned short* adjbf = (unsigned short*)(ws + ((size_t)16 << 20));  // 16 MB
  unsigned short* wt    = (unsigned short*)(ws + ((size_t)32 << 20));  //  2 MB
  unsigned short* sup2  = (unsigned short*)(ws + ((size_t)34 << 20));  // 16 MB

  k_prep<<<dim3(16640), dim3(256), 0, stream>>>(
      (const float4*)y, (const float4*)adj, (ushort4*)ybf, (ushort4*)adjbf, W, wt);
  k_gemm1<<<dim3(256), dim3(512), 0, stream>>>(wt, ybf, sup2);
  k_gemm2<<<dim3(256), dim3(512), 0, stream>>>(adjbf, sup2, x, sumrow, bias, out);
}